// Round 9
// baseline (582.438 us; speedup 1.0000x reference)
//
#include <hip/hip_runtime.h>

#define DFEAT 64
#define NG 64
#define TILE 128        // nodes per bucket/tile (bucket = id >> 7)
#define NBLK 256        // binning blocks
#define NBMAX 1024      // max buckets supported in LDS
#define NSB 1024        // stream blocks (S/T partials)

// ------- fused histograms: per-block-chunk bucket counts for tgt AND src -------
__global__ __launch_bounds__(256) void k_cntB(const int* __restrict__ row,
                                              const int* __restrict__ col,
                                              int* __restrict__ cnt_m,
                                              int* __restrict__ cnt_m2,
                                              int e, int nb, int chunk) {
  extern __shared__ int hist[];  // 2*nb ints
  int* histT = hist;
  int* histS = hist + nb;
  int tid = threadIdx.x;
  int blk = blockIdx.x;
  for (int b = tid; b < 2 * nb; b += 256) hist[b] = 0;
  __syncthreads();
  int lo = blk * chunk, hi = min(lo + chunk, e);
  for (int i = lo + tid; i < hi; i += 256) {
    atomicAdd(&histT[col[i] >> 7], 1);
    atomicAdd(&histS[row[i] >> 7], 1);
  }
  __syncthreads();
  for (int b = tid; b < nb; b += 256) {
    cnt_m[(size_t)blk * nb + b] = histT[b];
    cnt_m2[(size_t)blk * nb + b] = histS[b];
  }
}

// ------- per-bucket scan over blocks (in place) + totals, both matrices --------
__global__ __launch_bounds__(256) void k_colscanB(int* __restrict__ cnt_m,
                                                  int* __restrict__ gcount,
                                                  int* __restrict__ cnt_m2,
                                                  int* __restrict__ gcount2,
                                                  int nb) {
  __shared__ int sh[256];
  int tid = threadIdx.x;
  int bb = blockIdx.x;
  int* m = (bb < nb) ? cnt_m : cnt_m2;
  int* g = (bb < nb) ? gcount : gcount2;
  int b = (bb < nb) ? bb : bb - nb;
  int v = m[(size_t)tid * nb + b];
  sh[tid] = v;
  __syncthreads();
  for (int off = 1; off < 256; off <<= 1) {
    int t = (tid >= off) ? sh[tid - off] : 0;
    __syncthreads();
    sh[tid] += t;
    __syncthreads();
  }
  m[(size_t)tid * nb + b] = sh[tid] - v;
  if (tid == 255) g[b] = sh[255];
}

// ------- scan bucket totals -> base[0..nb], for both keys ----------------------
__global__ __launch_bounds__(1024) void k_bscanB(const int* __restrict__ gcount,
                                                 int* __restrict__ base,
                                                 const int* __restrict__ gcount2,
                                                 int* __restrict__ base2, int nb) {
  __shared__ int sh[1024];
  const int* g = (blockIdx.x == 0) ? gcount : gcount2;
  int* ba = (blockIdx.x == 0) ? base : base2;
  int tid = threadIdx.x;
  int v = (tid < nb) ? g[tid] : 0;
  sh[tid] = v;
  __syncthreads();
  for (int off = 1; off < 1024; off <<= 1) {
    int t = (tid >= off) ? sh[tid - off] : 0;
    __syncthreads();
    sh[tid] += t;
    __syncthreads();
  }
  if (tid < nb) ba[tid] = sh[tid] - v;
  if (tid == 0) ba[nb] = sh[1023];
}

// ------- place edges by TARGET tile, packed (src | tgtloc<<20) -----------------
__global__ __launch_bounds__(256) void k_bin2(const int* __restrict__ row,
                                              const int* __restrict__ col,
                                              const int* __restrict__ base,
                                              const int* __restrict__ cnt_m,
                                              int* __restrict__ pairs,
                                              int e, int nb, int chunk) {
  __shared__ int gl[NBMAX];
  __shared__ int lcur[NBMAX];
  int tid = threadIdx.x;
  int blk = blockIdx.x;
  for (int b = tid; b < nb; b += 256) {
    gl[b] = base[b] + cnt_m[(size_t)blk * nb + b];
    lcur[b] = 0;
  }
  __syncthreads();
  int lo = blk * chunk, hi = min(lo + chunk, e);
  for (int i = lo + tid; i < hi; i += 256) {
    int s = row[i], t = col[i];
    int b = t >> 7;
    int pos = gl[b] + atomicAdd(&lcur[b], 1);
    pairs[pos] = s | ((t & (TILE - 1)) << 20);
  }
}

// ------- per-tile CSR by target: node-ordered srcs, starts[], dinv -------------
__global__ __launch_bounds__(256) void k_csr(const int* __restrict__ pairs,
                                             const int* __restrict__ base,
                                             int* __restrict__ starts,
                                             int* __restrict__ srcs,
                                             float* __restrict__ dinv,
                                             int n, int e) {
  __shared__ int cnt[TILE];
  __shared__ int cur[TILE];
  __shared__ int sc[TILE];
  int tid = threadIdx.x;
  int b = blockIdx.x;
  int tile0 = b * TILE;
  if (tid < TILE) cnt[tid] = 0;
  __syncthreads();
  int e0 = base[b], e1 = base[b + 1];
  for (int i = e0 + tid; i < e1; i += 256)
    atomicAdd(&cnt[(unsigned)pairs[i] >> 20], 1);
  __syncthreads();
  int c = (tid < TILE) ? cnt[tid] : 0;
  if (tid < TILE) sc[tid] = c;
  __syncthreads();
  for (int off = 1; off < TILE; off <<= 1) {
    int t = (tid < TILE && tid >= off) ? sc[tid - off] : 0;
    __syncthreads();
    if (tid < TILE) sc[tid] += t;
    __syncthreads();
  }
  if (tid < TILE) {
    int excl = sc[tid] - c;
    cur[tid] = excl;
    int node = tile0 + tid;
    if (node < n) {
      starts[node] = e0 + excl;
      dinv[node] = rsqrtf(1.0f + (float)c);
    }
  }
  if (b == 0 && tid == 0) starts[n] = e;
  __syncthreads();
  for (int i = e0 + tid; i < e1; i += 256) {
    int p = pairs[i];
    int pos = atomicAdd(&cur[(unsigned)p >> 20], 1);
    srcs[e0 + pos] = p & 0xFFFFF;
  }
}

// ------- place edges by SOURCE tile with payload (src|g<<20, q=dr*dc) ----------
__global__ __launch_bounds__(256) void k_bin2b(const int* __restrict__ row,
                                               const int* __restrict__ col,
                                               const int* __restrict__ base2,
                                               const int* __restrict__ cnt_m2,
                                               const float* __restrict__ dinv,
                                               const int* __restrict__ batch,
                                               int* __restrict__ epk,
                                               float* __restrict__ qv,
                                               int e, int nb, int chunk) {
  __shared__ int gl[NBMAX];
  __shared__ int lcur[NBMAX];
  int tid = threadIdx.x;
  int blk = blockIdx.x;
  for (int b = tid; b < nb; b += 256) {
    gl[b] = base2[b] + cnt_m2[(size_t)blk * nb + b];
    lcur[b] = 0;
  }
  __syncthreads();
  int lo = blk * chunk, hi = min(lo + chunk, e);
  for (int i = lo + tid; i < hi; i += 256) {
    int s = row[i], t = col[i];
    int b = s >> 7;
    int pos = gl[b] + atomicAdd(&lcur[b], 1);
    epk[pos] = s | (batch[t] << 20);
    qv[pos] = dinv[s] * dinv[t];
  }
}

// ------- WW = W1@W2 (64x64), bw = b1^T @ W2 ------------------------------------
__global__ __launch_bounds__(256) void k_w12(const float* __restrict__ W1,
                                             const float* __restrict__ W2,
                                             const float* __restrict__ b1,
                                             float* __restrict__ WW,
                                             float* __restrict__ bw) {
  __shared__ float w1[4096], w2[4096];
  int tid = threadIdx.x;
  for (int i = tid; i < 4096; i += 256) { w1[i] = W1[i]; w2[i] = W2[i]; }
  __syncthreads();
  for (int p = tid; p < 4096; p += 256) {
    int k = p >> 6, d = p & 63;
    float a = 0.f;
    for (int m = 0; m < 64; ++m) a += w1[k * 64 + m] * w2[m * 64 + d];
    WW[p] = a;
  }
  if (tid < 64) {
    float a = 0.f;
    for (int k = 0; k < 64; ++k) a += b1[k] * w2[k * 64 + tid];
    bw[tid] = a;
  }
}

// ------- gather: z1 = A_hat * x  (R7 form: 2 nodes per wave, float2 lanes) -----
__global__ __launch_bounds__(256) void k_gather(const int* __restrict__ starts,
                                                const int* __restrict__ srcs,
                                                const float* __restrict__ dinv,
                                                const float* __restrict__ h,
                                                float* __restrict__ o, int n) {
  int node = blockIdx.x * 8 + (threadIdx.x >> 5);
  if (node >= n) return;
  int l2 = (threadIdx.x & 31) * 2;
  int s = starts[node];
  int e1 = starts[node + 1];
  int deg = e1 - s;
  float dc = dinv[node];
  float2 hs = *(const float2*)(&h[(size_t)node * 64 + l2]);
  float ax = 0.f, ay = 0.f;
  int j = 0;
  for (; j + 3 < deg; j += 4) {
    int r0 = srcs[s + j + 0];
    int r1 = srcs[s + j + 1];
    int r2 = srcs[s + j + 2];
    int r3 = srcs[s + j + 3];
    float w0 = dinv[r0], w1 = dinv[r1], w2 = dinv[r2], w3 = dinv[r3];
    float2 v0 = *(const float2*)(&h[(size_t)r0 * 64 + l2]);
    float2 v1 = *(const float2*)(&h[(size_t)r1 * 64 + l2]);
    float2 v2 = *(const float2*)(&h[(size_t)r2 * 64 + l2]);
    float2 v3 = *(const float2*)(&h[(size_t)r3 * 64 + l2]);
    ax += w0 * v0.x + w1 * v1.x + w2 * v2.x + w3 * v3.x;
    ay += w0 * v0.y + w1 * v1.y + w2 * v2.y + w3 * v3.y;
  }
  for (; j < deg; ++j) {
    int r = srcs[s + j];
    float w = dinv[r];
    float2 v = *(const float2*)(&h[(size_t)r * 64 + l2]);
    ax += w * v.x;
    ay += w * v.y;
  }
  float2 res;
  res.x = dc * dc * hs.x + dc * ax;
  res.y = dc * dc * hs.y + dc * ay;
  *(float2*)(&o[(size_t)node * 64 + l2]) = res;
}

// ------- stream: edge contributions to pooled S/T, LDS accumulate, partials ----
__global__ __launch_bounds__(256) void k_stream(const int* __restrict__ epk,
                                                const float* __restrict__ qv,
                                                const float* __restrict__ z1,
                                                float* __restrict__ pt, int e) {
  __shared__ float S[4096];
  __shared__ float T[64];
  int tid = threadIdx.x;
  int blk = blockIdx.x;
  for (int i = tid; i < 4096; i += 256) S[i] = 0.f;
  if (tid < 64) T[tid] = 0.f;
  __syncthreads();
  int chunk = (e + NSB - 1) / NSB;
  int c0 = blk * chunk, c1 = min(c0 + chunk, e);
  int lane = tid & 63;
  int w = tid >> 6;
  int span = c1 - c0;
  int per = (span + 3) >> 2;
  int lo = c0 + w * per, hi = min(lo + per, c1);
  int j = lo;
  for (; j + 4 <= hi; j += 4) {
    int e0 = epk[j], e1_ = epk[j + 1], e2_ = epk[j + 2], e3_ = epk[j + 3];
    float q0 = qv[j], q1 = qv[j + 1], q2 = qv[j + 2], q3 = qv[j + 3];
    float v0 = z1[(size_t)(e0 & 0xFFFFF) * 64 + lane];
    float v1 = z1[(size_t)(e1_ & 0xFFFFF) * 64 + lane];
    float v2 = z1[(size_t)(e2_ & 0xFFFFF) * 64 + lane];
    float v3 = z1[(size_t)(e3_ & 0xFFFFF) * 64 + lane];
    atomicAdd(&S[(e0 >> 20) * 64 + lane], q0 * v0);
    atomicAdd(&S[(e1_ >> 20) * 64 + lane], q1 * v1);
    atomicAdd(&S[(e2_ >> 20) * 64 + lane], q2 * v2);
    atomicAdd(&S[(e3_ >> 20) * 64 + lane], q3 * v3);
    if (lane == 0) {
      atomicAdd(&T[e0 >> 20], q0);
      atomicAdd(&T[e1_ >> 20], q1);
      atomicAdd(&T[e2_ >> 20], q2);
      atomicAdd(&T[e3_ >> 20], q3);
    }
  }
  for (; j < hi; ++j) {
    int e0 = epk[j];
    float q0 = qv[j];
    float v0 = z1[(size_t)(e0 & 0xFFFFF) * 64 + lane];
    atomicAdd(&S[(e0 >> 20) * 64 + lane], q0 * v0);
    if (lane == 0) atomicAdd(&T[e0 >> 20], q0);
  }
  __syncthreads();
  float* o = pt + (size_t)blk * 4160;
  for (int i = tid; i < 4096; i += 256) o[i] = S[i];
  if (tid < 64) o[4096 + tid] = T[tid];
}

// ------- reduce partials into S/T (atomic: pool2 also adds self terms) ---------
__global__ __launch_bounds__(256) void k_reduceS(const float* __restrict__ pt,
                                                 float* __restrict__ S,
                                                 float* __restrict__ T) {
  int gid = blockIdx.x * 256 + threadIdx.x;
  if (gid >= 4160 * 4) return;
  int elem = gid % 4160;
  int part = gid / 4160;           // 0..3, each sums NSB/4 partials
  int p0 = part * (NSB / 4);
  float a = 0.f;
  for (int k = 0; k < NSB / 4; ++k) a += pt[(size_t)(p0 + k) * 4160 + elem];
  if (elem < 4096) unsafeAtomicAdd(&S[elem], a);
  else unsafeAtomicAdd(&T[elem - 4096], a);
}

// ------- pool self terms: S[g] += dinv^2*z1 row; T[g] += dinv^2; cnt -----------
__global__ void k_pool2(const float* __restrict__ z1, const float* __restrict__ dinv,
                        const int* __restrict__ batch, float* __restrict__ S,
                        float* __restrict__ T, float* __restrict__ cntf, int n) {
  int d = threadIdx.x;
  int start = blockIdx.x * 64;
  if (start >= n) return;
  int end = min(start + 64, n);
  int curg = batch[start];
  float acc = 0.f, cnt = 0.f, ua = 0.f;
  for (int i = start; i < end; ++i) {
    int g = batch[i];
    if (g != curg) {
      unsafeAtomicAdd(&S[curg * 64 + d], acc);
      if (d == 0) {
        unsafeAtomicAdd(&cntf[curg], cnt);
        unsafeAtomicAdd(&T[curg], ua);
      }
      acc = 0.f; cnt = 0.f; ua = 0.f;
      curg = g;
    }
    float di = dinv[i];
    float wgt = di * di;
    acc += wgt * z1[(size_t)i * 64 + d];
    if (d == 0) { cnt += 1.f; ua += wgt; }
  }
  unsafeAtomicAdd(&S[curg * 64 + d], acc);
  if (d == 0) {
    unsafeAtomicAdd(&cntf[curg], cnt);
    unsafeAtomicAdd(&T[curg], ua);
  }
}

// ------- final: out[g] = (S[g]@WW + T[g]*bw)/cnt + b2 --------------------------
__global__ __launch_bounds__(256) void k_final2(const float* __restrict__ S,
                                                const float* __restrict__ T,
                                                const float* __restrict__ cntf,
                                                const float* __restrict__ WW,
                                                const float* __restrict__ bw,
                                                const float* __restrict__ b2,
                                                float* __restrict__ out) {
  __shared__ float sS[4096], sW[4096];
  int tid = threadIdx.x;
  for (int i = tid; i < 4096; i += 256) { sS[i] = S[i]; sW[i] = WW[i]; }
  __syncthreads();
  for (int p = tid; p < 4096; p += 256) {
    int g = p >> 6, d = p & 63;
    float a = 0.f;
    for (int k = 0; k < 64; ++k) a += sS[g * 64 + k] * sW[k * 64 + d];
    float c = fmaxf(cntf[g], 1.0f);
    out[p] = (a + T[g] * bw[d]) / c + b2[d];
  }
}

extern "C" void kernel_launch(void* const* d_in, const int* in_sizes, int n_in,
                              void* d_out, int out_size, void* d_ws, size_t ws_size,
                              hipStream_t stream) {
  const float* x = (const float*)d_in[0];
  const int* ei = (const int*)d_in[1];
  const int* bat = (const int*)d_in[2];
  const float* W1 = (const float*)d_in[3];
  const float* b1 = (const float*)d_in[4];
  const float* W2 = (const float*)d_in[5];
  const float* b2 = (const float*)d_in[6];
  float* out = (float*)d_out;

  int n = in_sizes[0] / 64;  // 100000
  int e = in_sizes[1] / 2;   // 1000000
  const int* rowp = ei;      // sources
  const int* colp = ei + e;  // targets
  int nb = (n + TILE - 1) / TILE;      // 782 buckets (< NBMAX)
  int chunk = (e + NBLK - 1) / NBLK;   // edges per binning block

  char* ws = (char*)d_ws;
  size_t off = 0;
  auto alloc = [&](size_t elems) {
    void* p = ws + off;
    off += ((elems * 4 + 255) & ~(size_t)255);
    return p;
  };
  float* S = (float*)alloc(NG * DFEAT);
  float* cntf = (float*)alloc(NG);
  float* T = (float*)alloc(NG);
  size_t zbytes = off;
  int* gcount = (int*)alloc(nb);
  int* base = (int*)alloc(nb + 1);
  int* gcount2 = (int*)alloc(nb);
  int* base2 = (int*)alloc(nb + 1);
  int* cnt_m = (int*)alloc((size_t)NBLK * nb);
  int* cnt_m2 = (int*)alloc((size_t)NBLK * nb);
  float* dinv = (float*)alloc(n);
  int* starts = (int*)alloc(n + 1);
  int* srcs = (int*)alloc(e);
  int* epk = (int*)alloc(e);
  float* qv = (float*)alloc(e);
  float* WW = (float*)alloc(DFEAT * DFEAT);
  float* bw = (float*)alloc(DFEAT);
  float* pt = (float*)alloc((size_t)NSB * 4160);
  float* z1 = (float*)alloc((size_t)n * 64);
  int* pairs = (int*)z1;  // target-major pairs; dead after k_csr, before z1 write

  int nbw = (n + 7) / 8;  // gather: 2 nodes/wave, 8 per block

  hipMemsetAsync(S, 0, zbytes, stream);
  k_cntB<<<NBLK, 256, 2 * nb * sizeof(int), stream>>>(rowp, colp, cnt_m, cnt_m2, e, nb, chunk);
  k_colscanB<<<2 * nb, 256, 0, stream>>>(cnt_m, gcount, cnt_m2, gcount2, nb);
  k_bscanB<<<2, 1024, 0, stream>>>(gcount, base, gcount2, base2, nb);
  k_bin2<<<NBLK, 256, 0, stream>>>(rowp, colp, base, cnt_m, pairs, e, nb, chunk);
  k_csr<<<nb, 256, 0, stream>>>(pairs, base, starts, srcs, dinv, n, e);
  k_bin2b<<<NBLK, 256, 0, stream>>>(rowp, colp, base2, cnt_m2, dinv, bat, epk, qv, e, nb, chunk);
  k_w12<<<1, 256, 0, stream>>>(W1, W2, b1, WW, bw);

  // layer 1: z1 = A_hat * x  (overwrites pairs alias — safe after k_csr)
  k_gather<<<nbw, 256, 0, stream>>>(starts, srcs, dinv, x, z1, n);

  // layer 2 (pooled, scatter form): edge terms via stream, self terms via pool2
  k_stream<<<NSB, 256, 0, stream>>>(epk, qv, z1, pt, e);
  k_reduceS<<<(4160 * 4 + 255) / 256, 256, 0, stream>>>(pt, S, T);
  k_pool2<<<(n + 63) / 64, 64, 0, stream>>>(z1, dinv, bat, S, T, cntf, n);
  k_final2<<<1, 256, 0, stream>>>(S, T, cntf, WW, bw, b2, out);
}

// Round 10
// 233.898 us; speedup vs baseline: 2.4901x; 2.4901x over previous
//
#include <hip/hip_runtime.h>
#include <hip/hip_fp16.h>

#define DFEAT 64
#define NG 64
#define TILE 128        // nodes per bucket/tile (bucket = tgt >> 7)
#define NBLK 256        // binning blocks
#define NBMAX 1024      // max buckets supported in LDS

// ---------------- pass A: per-block-chunk bucket histogram -> cnt_m[blk][b] -----
__global__ __launch_bounds__(256) void k_cnt(const int* __restrict__ col,
                                             int* __restrict__ cnt_m,
                                             int e, int nb, int chunk) {
  __shared__ int hist[NBMAX];
  int tid = threadIdx.x;
  int blk = blockIdx.x;
  for (int b = tid; b < nb; b += 256) hist[b] = 0;
  __syncthreads();
  int lo = blk * chunk, hi = min(lo + chunk, e);
  for (int i = lo + tid; i < hi; i += 256)
    atomicAdd(&hist[col[i] >> 7], 1);
  __syncthreads();
  for (int b = tid; b < nb; b += 256)
    cnt_m[(size_t)blk * nb + b] = hist[b];
}

// ---------------- pass B: per-bucket scan over blocks (in place) + totals -------
__global__ __launch_bounds__(256) void k_colscan(int* __restrict__ cnt_m,
                                                 int* __restrict__ gcount, int nb) {
  __shared__ int sh[256];
  int tid = threadIdx.x;
  int b = blockIdx.x;
  int v = cnt_m[(size_t)tid * nb + b];
  sh[tid] = v;
  __syncthreads();
  for (int off = 1; off < 256; off <<= 1) {
    int t = (tid >= off) ? sh[tid - off] : 0;
    __syncthreads();
    sh[tid] += t;
    __syncthreads();
  }
  cnt_m[(size_t)tid * nb + b] = sh[tid] - v;  // exclusive over blocks
  if (tid == 255) gcount[b] = sh[255];
}

// ---------------- scan bucket totals -> base[0..nb] ----------------------------
__global__ __launch_bounds__(1024) void k_bscan(const int* __restrict__ gcount,
                                                int* __restrict__ base, int nb) {
  __shared__ int sh[1024];
  int tid = threadIdx.x;
  int v = (tid < nb) ? gcount[tid] : 0;
  sh[tid] = v;
  __syncthreads();
  for (int off = 1; off < 1024; off <<= 1) {
    int t = (tid >= off) ? sh[tid - off] : 0;
    __syncthreads();
    sh[tid] += t;
    __syncthreads();
  }
  if (tid < nb) base[tid] = sh[tid] - v;
  if (tid == 0) base[nb] = sh[1023];
}

// ---------------- pass C: place edges, LDS cursors only, packed payload --------
// pairs[pos] = src | ((tgt & 127) << 20)   (requires n < 2^20)
__global__ __launch_bounds__(256) void k_bin2(const int* __restrict__ row,
                                              const int* __restrict__ col,
                                              const int* __restrict__ base,
                                              const int* __restrict__ cnt_m,
                                              int* __restrict__ pairs,
                                              int e, int nb, int chunk) {
  __shared__ int gl[NBMAX];
  __shared__ int lcur[NBMAX];
  int tid = threadIdx.x;
  int blk = blockIdx.x;
  for (int b = tid; b < nb; b += 256) {
    gl[b] = base[b] + cnt_m[(size_t)blk * nb + b];
    lcur[b] = 0;
  }
  __syncthreads();
  int lo = blk * chunk, hi = min(lo + chunk, e);
  for (int i = lo + tid; i < hi; i += 256) {
    int s = row[i], t = col[i];
    int b = t >> 7;
    int pos = gl[b] + atomicAdd(&lcur[b], 1);
    pairs[pos] = s | ((t & (TILE - 1)) << 20);
  }
}

// ---------------- per-tile CSR: node-ordered srcs, starts[], dinv ---------------
__global__ __launch_bounds__(256) void k_csr(const int* __restrict__ pairs,
                                             const int* __restrict__ base,
                                             int* __restrict__ starts,
                                             int* __restrict__ srcs,
                                             float* __restrict__ dinv,
                                             int n, int e) {
  __shared__ int cnt[TILE];
  __shared__ int cur[TILE];
  __shared__ int sc[TILE];
  int tid = threadIdx.x;
  int b = blockIdx.x;
  int tile0 = b * TILE;
  if (tid < TILE) cnt[tid] = 0;
  __syncthreads();
  int e0 = base[b], e1 = base[b + 1];
  for (int i = e0 + tid; i < e1; i += 256)
    atomicAdd(&cnt[(unsigned)pairs[i] >> 20], 1);
  __syncthreads();
  int c = (tid < TILE) ? cnt[tid] : 0;
  if (tid < TILE) sc[tid] = c;
  __syncthreads();
  for (int off = 1; off < TILE; off <<= 1) {
    int t = (tid < TILE && tid >= off) ? sc[tid - off] : 0;
    __syncthreads();
    if (tid < TILE) sc[tid] += t;
    __syncthreads();
  }
  if (tid < TILE) {
    int excl = sc[tid] - c;
    cur[tid] = excl;
    int node = tile0 + tid;
    if (node < n) {
      starts[node] = e0 + excl;
      dinv[node] = rsqrtf(1.0f + (float)c);
    }
  }
  if (b == 0 && tid == 0) starts[n] = e;
  __syncthreads();
  for (int i = e0 + tid; i < e1; i += 256) {
    int p = pairs[i];
    int pos = atomicAdd(&cur[(unsigned)p >> 20], 1);
    srcs[e0 + pos] = p & 0xFFFFF;
  }
}

// ---------------- x (fp32) -> xh (fp16), element-pair wise ----------------------
__global__ void k_half(const float* __restrict__ x, __half2* __restrict__ xh,
                       int n32) {
  int i = blockIdx.x * 256 + threadIdx.x;
  if (i < n32) {
    float2 v = ((const float2*)x)[i];
    xh[i] = __float22half2_rn(v);
  }
}

// ---------------- WW = W1@W2 (64x64), bw = b1^T @ W2 ----------------------------
__global__ __launch_bounds__(256) void k_w12(const float* __restrict__ W1,
                                             const float* __restrict__ W2,
                                             const float* __restrict__ b1,
                                             float* __restrict__ WW,
                                             float* __restrict__ bw) {
  __shared__ float w1[4096], w2[4096];
  int tid = threadIdx.x;
  for (int i = tid; i < 4096; i += 256) { w1[i] = W1[i]; w2[i] = W2[i]; }
  __syncthreads();
  for (int p = tid; p < 4096; p += 256) {
    int k = p >> 6, d = p & 63;
    float a = 0.f;
    for (int m = 0; m < 64; ++m) a += w1[k * 64 + m] * w2[m * 64 + d];
    WW[p] = a;
  }
  if (tid < 64) {
    float a = 0.f;
    for (int k = 0; k < 64; ++k) a += b1[k] * w2[k * 64 + tid];
    bw[tid] = a;
  }
}

// ------- gather1: z1h = A_hat * xh (fp16 in/out), fused u = A_hat*1 -------------
// 2 nodes per wave; 32 lanes per node, each lane one __half2 (4 B) of the row.
__global__ __launch_bounds__(256) void k_gather1(const int* __restrict__ starts,
                                                 const int* __restrict__ srcs,
                                                 const float* __restrict__ dinv,
                                                 const __half2* __restrict__ xh,
                                                 __half2* __restrict__ z1h,
                                                 float* __restrict__ u, int n) {
  int node = blockIdx.x * 8 + (threadIdx.x >> 5);
  if (node >= n) return;
  int lh = threadIdx.x & 31;
  int s = starts[node];
  int deg = starts[node + 1] - s;
  float dc = dinv[node];
  float2 hs = __half22float2(xh[(size_t)node * 32 + lh]);
  float ax = 0.f, ay = 0.f, wsum = 0.f;
  int j = 0;
  for (; j + 3 < deg; j += 4) {
    int r0 = srcs[s + j + 0];
    int r1 = srcs[s + j + 1];
    int r2 = srcs[s + j + 2];
    int r3 = srcs[s + j + 3];
    float w0 = dinv[r0], w1 = dinv[r1], w2 = dinv[r2], w3 = dinv[r3];
    float2 v0 = __half22float2(xh[(size_t)r0 * 32 + lh]);
    float2 v1 = __half22float2(xh[(size_t)r1 * 32 + lh]);
    float2 v2 = __half22float2(xh[(size_t)r2 * 32 + lh]);
    float2 v3 = __half22float2(xh[(size_t)r3 * 32 + lh]);
    ax += w0 * v0.x + w1 * v1.x + w2 * v2.x + w3 * v3.x;
    ay += w0 * v0.y + w1 * v1.y + w2 * v2.y + w3 * v3.y;
    wsum += w0 + w1 + w2 + w3;
  }
  for (; j < deg; ++j) {
    int r = srcs[s + j];
    float w = dinv[r];
    float2 v = __half22float2(xh[(size_t)r * 32 + lh]);
    ax += w * v.x;
    ay += w * v.y;
    wsum += w;
  }
  float2 res;
  res.x = dc * dc * hs.x + dc * ax;
  res.y = dc * dc * hs.y + dc * ay;
  z1h[(size_t)node * 32 + lh] = __float22half2_rn(res);
  if (lh == 0) u[node] = dc * (dc + wsum);
}

// ------- gather2: z2 (fp32) = A_hat * z1h (fp16 in) -----------------------------
__global__ __launch_bounds__(256) void k_gather2(const int* __restrict__ starts,
                                                 const int* __restrict__ srcs,
                                                 const float* __restrict__ dinv,
                                                 const __half2* __restrict__ z1h,
                                                 float* __restrict__ z2, int n) {
  int node = blockIdx.x * 8 + (threadIdx.x >> 5);
  if (node >= n) return;
  int lh = threadIdx.x & 31;
  int s = starts[node];
  int deg = starts[node + 1] - s;
  float dc = dinv[node];
  float2 hs = __half22float2(z1h[(size_t)node * 32 + lh]);
  float ax = 0.f, ay = 0.f;
  int j = 0;
  for (; j + 3 < deg; j += 4) {
    int r0 = srcs[s + j + 0];
    int r1 = srcs[s + j + 1];
    int r2 = srcs[s + j + 2];
    int r3 = srcs[s + j + 3];
    float w0 = dinv[r0], w1 = dinv[r1], w2 = dinv[r2], w3 = dinv[r3];
    float2 v0 = __half22float2(z1h[(size_t)r0 * 32 + lh]);
    float2 v1 = __half22float2(z1h[(size_t)r1 * 32 + lh]);
    float2 v2 = __half22float2(z1h[(size_t)r2 * 32 + lh]);
    float2 v3 = __half22float2(z1h[(size_t)r3 * 32 + lh]);
    ax += w0 * v0.x + w1 * v1.x + w2 * v2.x + w3 * v3.x;
    ay += w0 * v0.y + w1 * v1.y + w2 * v2.y + w3 * v3.y;
  }
  for (; j < deg; ++j) {
    int r = srcs[s + j];
    float w = dinv[r];
    float2 v = __half22float2(z1h[(size_t)r * 32 + lh]);
    ax += w * v.x;
    ay += w * v.y;
  }
  float2 res;
  res.x = dc * dc * hs.x + dc * ax;
  res.y = dc * dc * hs.y + dc * ay;
  *(float2*)(&z2[(size_t)node * 64 + lh * 2]) = res;
}

// ---------------- pool z2 rows, u, and counts (batch sorted) --------------------
__global__ void k_pool2(const float* __restrict__ z2, const float* __restrict__ u,
                        const int* __restrict__ batch, float* __restrict__ S,
                        float* __restrict__ T, float* __restrict__ cntf, int n) {
  int d = threadIdx.x;
  int start = blockIdx.x * 64;
  if (start >= n) return;
  int end = min(start + 64, n);
  int curg = batch[start];
  float acc = 0.f, cnt = 0.f, ua = 0.f;
  for (int i = start; i < end; ++i) {
    int g = batch[i];
    if (g != curg) {
      unsafeAtomicAdd(&S[curg * 64 + d], acc);
      if (d == 0) {
        unsafeAtomicAdd(&cntf[curg], cnt);
        unsafeAtomicAdd(&T[curg], ua);
      }
      acc = 0.f; cnt = 0.f; ua = 0.f;
      curg = g;
    }
    acc += z2[(size_t)i * 64 + d];
    if (d == 0) { cnt += 1.f; ua += u[i]; }
  }
  unsafeAtomicAdd(&S[curg * 64 + d], acc);
  if (d == 0) {
    unsafeAtomicAdd(&cntf[curg], cnt);
    unsafeAtomicAdd(&T[curg], ua);
  }
}

// ---------------- final: out[g] = (S[g]@WW + T[g]*bw)/cnt + b2 ------------------
__global__ __launch_bounds__(256) void k_final2(const float* __restrict__ S,
                                                const float* __restrict__ T,
                                                const float* __restrict__ cntf,
                                                const float* __restrict__ WW,
                                                const float* __restrict__ bw,
                                                const float* __restrict__ b2,
                                                float* __restrict__ out) {
  __shared__ float sS[4096], sW[4096];
  int tid = threadIdx.x;
  for (int i = tid; i < 4096; i += 256) { sS[i] = S[i]; sW[i] = WW[i]; }
  __syncthreads();
  for (int p = tid; p < 4096; p += 256) {
    int g = p >> 6, d = p & 63;
    float a = 0.f;
    for (int k = 0; k < 64; ++k) a += sS[g * 64 + k] * sW[k * 64 + d];
    float c = fmaxf(cntf[g], 1.0f);
    out[p] = (a + T[g] * bw[d]) / c + b2[d];
  }
}

extern "C" void kernel_launch(void* const* d_in, const int* in_sizes, int n_in,
                              void* d_out, int out_size, void* d_ws, size_t ws_size,
                              hipStream_t stream) {
  const float* x = (const float*)d_in[0];
  const int* ei = (const int*)d_in[1];
  const int* bat = (const int*)d_in[2];
  const float* W1 = (const float*)d_in[3];
  const float* b1 = (const float*)d_in[4];
  const float* W2 = (const float*)d_in[5];
  const float* b2 = (const float*)d_in[6];
  float* out = (float*)d_out;

  int n = in_sizes[0] / 64;  // 100000
  int e = in_sizes[1] / 2;   // 1000000
  const int* rowp = ei;      // sources
  const int* colp = ei + e;  // targets
  int nb = (n + TILE - 1) / TILE;      // 782 buckets (< NBMAX)
  int chunk = (e + NBLK - 1) / NBLK;   // edges per binning block

  // workspace (4B alloc units): [S][cntf][T] zeroed | gcount, base, cnt_m,
  // dinv, starts, srcs, u, WW, bw, xh, z1h, z2 (pairs alias z2).  ~47 MB.
  char* ws = (char*)d_ws;
  size_t off = 0;
  auto alloc = [&](size_t elems) {
    void* p = ws + off;
    off += ((elems * 4 + 255) & ~(size_t)255);
    return p;
  };
  float* S = (float*)alloc(NG * DFEAT);
  float* cntf = (float*)alloc(NG);
  float* T = (float*)alloc(NG);
  size_t zbytes = off;
  int* gcount = (int*)alloc(nb);
  int* base = (int*)alloc(nb + 1);
  int* cnt_m = (int*)alloc((size_t)NBLK * nb);
  float* dinv = (float*)alloc(n);
  int* starts = (int*)alloc(n + 1);
  int* srcs = (int*)alloc(e);
  float* u = (float*)alloc(n);
  float* WW = (float*)alloc(DFEAT * DFEAT);
  float* bw = (float*)alloc(DFEAT);
  __half2* xh = (__half2*)alloc((size_t)n * 32);   // n*64 halves
  __half2* z1h = (__half2*)alloc((size_t)n * 32);  // n*64 halves
  float* z2 = (float*)alloc((size_t)n * 64);
  int* pairs = (int*)z2;  // dead after k_csr; z2 first written by gather2

  int nbw = (n + 7) / 8;  // gathers: 2 nodes/wave, 8 per block
  int n32 = n * 32;       // half2 count

  hipMemsetAsync(S, 0, zbytes, stream);
  k_cnt<<<NBLK, 256, 0, stream>>>(colp, cnt_m, e, nb, chunk);
  k_colscan<<<nb, 256, 0, stream>>>(cnt_m, gcount, nb);
  k_bscan<<<1, 1024, 0, stream>>>(gcount, base, nb);
  k_bin2<<<NBLK, 256, 0, stream>>>(rowp, colp, base, cnt_m, pairs, e, nb, chunk);
  k_csr<<<nb, 256, 0, stream>>>(pairs, base, starts, srcs, dinv, n, e);
  k_half<<<(n32 + 255) / 256, 256, 0, stream>>>(x, xh, n32);
  k_w12<<<1, 256, 0, stream>>>(W1, W2, b1, WW, bw);

  // layer 1: z1h = A_hat * xh (+ fused u) ; layer 2: z2 = A_hat * z1h
  k_gather1<<<nbw, 256, 0, stream>>>(starts, srcs, dinv, xh, z1h, u, n);
  k_gather2<<<nbw, 256, 0, stream>>>(starts, srcs, dinv, z1h, z2, n);

  // pool + tiny final matmul
  k_pool2<<<(n + 63) / 64, 64, 0, stream>>>(z2, u, bat, S, T, cntf, n);
  k_final2<<<1, 256, 0, stream>>>(S, T, cntf, WW, bw, b2, out);
}